// Round 1
// baseline (103.117 us; speedup 1.0000x reference)
//
#include <hip/hip_runtime.h>

#define KEPS 1e-16f

__device__ __forceinline__ float fast_sigmoid(float v) {
    // 1 / (1 + exp(-v)); v_exp + v_rcp, ~1ulp each — far within 0.015 absmax.
    return __builtin_amdgcn_rcpf(1.0f + __expf(-v));
}

__global__ __launch_bounds__(256) void kitsune_fused(
    const float* __restrict__ x,           // [B][100]
    const float* __restrict__ tail_enc_w,  // [10][8][10]
    const float* __restrict__ tail_enc_b,  // [10][8]
    const float* __restrict__ tail_dec_w,  // [10][10][8]
    const float* __restrict__ tail_dec_b,  // [10][10]
    const float* __restrict__ tail_nmin,   // [10][10]
    const float* __restrict__ tail_nmax,   // [10][10]
    const float* __restrict__ head_enc_w,  // [8][10]
    const float* __restrict__ head_enc_b,  // [8]
    const float* __restrict__ head_dec_w,  // [10][8]
    const float* __restrict__ head_dec_b,  // [10]
    const float* __restrict__ head_nmin,   // [10]
    const float* __restrict__ head_nmax,   // [10]
    float* __restrict__ out_xhat,          // [B][10]
    float* __restrict__ out_t,             // [B][10]
    int B)
{
    const int b = blockIdx.x * blockDim.x + threadIdx.x;
    if (b >= B) return;

    const float* xrow = x + (size_t)b * 100;

    float tails[10];

    // ---- 10 tail autoencoders (loop NOT unrolled: wave-uniform weight
    // indices -> scalar loads; keeps I$ and VGPR pressure low) ----
    for (int c = 0; c < 10; ++c) {
        // load this cluster's 10 inputs (8B-aligned) and normalise
        float xn[10];
        #pragma unroll
        for (int j = 0; j < 5; ++j) {
            float2 v = *reinterpret_cast<const float2*>(xrow + c * 10 + j * 2);
            xn[2 * j]     = v.x;
            xn[2 * j + 1] = v.y;
        }
        #pragma unroll
        for (int f = 0; f < 10; ++f) {
            float nmin = tail_nmin[c * 10 + f];
            float r = __builtin_amdgcn_rcpf(tail_nmax[c * 10 + f] - nmin + KEPS);
            xn[f] = (xn[f] - nmin) * r;
        }

        // encoder: h = sigmoid(W_enc[c] @ xn + b_enc[c])   [8]
        float h[8];
        #pragma unroll
        for (int i = 0; i < 8; ++i) {
            float acc = tail_enc_b[c * 8 + i];
            #pragma unroll
            for (int f = 0; f < 10; ++f)
                acc = fmaf(tail_enc_w[(c * 8 + i) * 10 + f], xn[f], acc);
            h[i] = fast_sigmoid(acc);
        }

        // decoder + RMSE accumulation
        float ss = 0.0f;
        #pragma unroll
        for (int f = 0; f < 10; ++f) {
            float acc = tail_dec_b[c * 10 + f];
            #pragma unroll
            for (int i = 0; i < 8; ++i)
                acc = fmaf(tail_dec_w[(c * 10 + f) * 8 + i], h[i], acc);
            float rec = fast_sigmoid(acc);
            float d = rec - xn[f];
            ss = fmaf(d, d, ss);
        }
        float loss = __fsqrt_rn(ss * 0.1f);
        tails[c] = (loss == 0.0f) ? 0.01f : loss;
    }

    // ---- head ----
    float t[10];
    #pragma unroll
    for (int c = 0; c < 10; ++c) {
        float nmin = head_nmin[c];
        float r = __builtin_amdgcn_rcpf(head_nmax[c] - nmin + KEPS);
        t[c] = (tails[c] - nmin) * r;
    }

    float hh[8];
    #pragma unroll
    for (int i = 0; i < 8; ++i) {
        float acc = head_enc_b[i];
        #pragma unroll
        for (int c = 0; c < 10; ++c)
            acc = fmaf(head_enc_w[i * 10 + c], t[c], acc);
        hh[i] = fast_sigmoid(acc);
    }

    float xh[10];
    #pragma unroll
    for (int c = 0; c < 10; ++c) {
        float acc = head_dec_b[c];
        #pragma unroll
        for (int i = 0; i < 8; ++i)
            acc = fmaf(head_dec_w[c * 8 + i], hh[i], acc);
        xh[c] = fast_sigmoid(acc);
    }

    // ---- stores (8B-aligned float2) ----
    float* po = out_xhat + (size_t)b * 10;
    float* pt = out_t    + (size_t)b * 10;
    #pragma unroll
    for (int j = 0; j < 5; ++j) {
        *reinterpret_cast<float2*>(po + 2 * j) = make_float2(xh[2 * j], xh[2 * j + 1]);
        *reinterpret_cast<float2*>(pt + 2 * j) = make_float2(t[2 * j], t[2 * j + 1]);
    }
}

extern "C" void kernel_launch(void* const* d_in, const int* in_sizes, int n_in,
                              void* d_out, int out_size, void* d_ws, size_t ws_size,
                              hipStream_t stream) {
    const float* x          = (const float*)d_in[0];
    const float* tail_enc_w = (const float*)d_in[1];
    const float* tail_enc_b = (const float*)d_in[2];
    const float* tail_dec_w = (const float*)d_in[3];
    const float* tail_dec_b = (const float*)d_in[4];
    const float* tail_nmin  = (const float*)d_in[5];
    const float* tail_nmax  = (const float*)d_in[6];
    const float* head_enc_w = (const float*)d_in[7];
    const float* head_enc_b = (const float*)d_in[8];
    const float* head_dec_w = (const float*)d_in[9];
    const float* head_dec_b = (const float*)d_in[10];
    const float* head_nmin  = (const float*)d_in[11];
    const float* head_nmax  = (const float*)d_in[12];

    const int B = in_sizes[0] / 100;

    float* out_xhat = (float*)d_out;             // [B][10], first in tuple
    float* out_t    = out_xhat + (size_t)B * 10; // [B][10], second in tuple

    const int block = 256;
    const int grid  = (B + block - 1) / block;
    kitsune_fused<<<grid, block, 0, stream>>>(
        x, tail_enc_w, tail_enc_b, tail_dec_w, tail_dec_b,
        tail_nmin, tail_nmax, head_enc_w, head_enc_b,
        head_dec_w, head_dec_b, head_nmin, head_nmax,
        out_xhat, out_t, B);
}